// Round 1
// baseline (1004.810 us; speedup 1.0000x reference)
//
#include <hip/hip_runtime.h>
#include <math.h>

#define B     4096
#define ND    13
#define NS    26
#define NF    39
#define EMB   8
#define VOCAB 100000

// ---------------- workspace layout (floats) ----------------
// emb  : B*NS*EMB           = 851968
// X1   : B*128*EMB          = 4194304
// lin  : B                  = 4096
// s1   : B                  = 4096
// s2   : B                  = 4096
// W0t  : 26*26*128          = 86528
// W1t  : 128*26*128         = 425984
#define OFF_EMB 0
#define OFF_X1  851968
#define OFF_LIN 5046272
#define OFF_S1  5050368
#define OFF_S2  5054464
#define OFF_W0T 5058560
#define OFF_W1T 5145088
// total 5571072 floats = 22.3 MB

// Transpose CIN weights to [p=(i*26+j)][o] so the per-o inner loop is coalesced.
__global__ void k_transpose(const float* __restrict__ W0, const float* __restrict__ W1,
                            float* __restrict__ W0t, float* __restrict__ W1t) {
    int t = blockIdx.x * 256 + threadIdx.x;
    if (t < 676 * 128) {
        int o = t & 127, p = t >> 7;
        W0t[t] = W0[o * 676 + p];
    } else {
        int t2 = t - 676 * 128;
        if (t2 < 3328 * 128) {
            int o = t2 & 127, p = t2 >> 7;
            W1t[t2] = W1[o * 3328 + p];
        }
    }
}

// Embedding gather + linear term.
__global__ void k_gather(const float* __restrict__ inputs, const float* __restrict__ tables,
                         const float* __restrict__ lW, const float* __restrict__ lb,
                         float* __restrict__ emb, float* __restrict__ lin) {
    int t = blockIdx.x * 256 + threadIdx.x;
    if (t < B * NS * EMB) {
        int e = t & 7;
        int rest = t >> 3;
        int f = rest % NS;
        int b = rest / NS;
        int idx = (int)inputs[b * NF + ND + f];
        emb[t] = tables[((long)f * VOCAB + idx) * EMB + e];
    }
    if (t < B) {
        float acc = lb[0];
        for (int c = 0; c < NF; c++) acc += inputs[t * NF + c] * lW[c];
        lin[t] = acc;
    }
}

// CIN layer 0: X1[b,o,k] = sum_{i,j} W0[o,i,j] X0[b,i,k] X0[b,j,k] + b0[o]
// Also fused epilogue: s1[b] = sum_o clw[o] * sum_k X1[b,o,k]
__global__ __launch_bounds__(128) void k_cin0(const float* __restrict__ emb,
                                              const float* __restrict__ W0t,
                                              const float* __restrict__ b0,
                                              const float* __restrict__ clw,
                                              float* __restrict__ X1g,
                                              float* __restrict__ s1) {
    __shared__ alignas(16) float X0s[NS * EMB];      // 208
    __shared__ alignas(16) float Zs[26 * 26 * 8];    // 5408 = 21.6 KB
    __shared__ float red[2];
    int b = blockIdx.x, tid = threadIdx.x;
    for (int t = tid; t < NS * EMB; t += 128) X0s[t] = emb[b * (NS * EMB) + t];
    __syncthreads();
    for (int t = tid; t < 5408; t += 128) {
        int k = t & 7, p = t >> 3;
        int i = p / 26, j = p - i * 26;
        Zs[t] = X0s[i * 8 + k] * X0s[j * 8 + k];
    }
    __syncthreads();
    int o = tid;
    float a0 = 0, a1 = 0, a2 = 0, a3 = 0, a4 = 0, a5 = 0, a6 = 0, a7 = 0;
    const float4* Zv = (const float4*)Zs;
    const float* wp = W0t + o;
#pragma unroll 4
    for (int p = 0; p < 676; p++) {
        float w = wp[p * 128];
        float4 za = Zv[2 * p], zb = Zv[2 * p + 1];
        a0 += w * za.x; a1 += w * za.y; a2 += w * za.z; a3 += w * za.w;
        a4 += w * zb.x; a5 += w * zb.y; a6 += w * zb.z; a7 += w * zb.w;
    }
    float bias = b0[o];
    a0 += bias; a1 += bias; a2 += bias; a3 += bias;
    a4 += bias; a5 += bias; a6 += bias; a7 += bias;
    float* xo = X1g + (long)b * 1024 + o * 8;
    xo[0] = a0; xo[1] = a1; xo[2] = a2; xo[3] = a3;
    xo[4] = a4; xo[5] = a5; xo[6] = a6; xo[7] = a7;
    float s = (a0 + a1 + a2 + a3) + (a4 + a5 + a6 + a7);
    float c = s * clw[o];
    for (int off = 32; off; off >>= 1) c += __shfl_down(c, off, 64);
    if ((tid & 63) == 0) red[tid >> 6] = c;
    __syncthreads();
    if (tid == 0) s1[b] = red[0] + red[1];
}

// CIN layer 1: X2[b,o,k] = sum_{i,j} W1[o,i,j] X1[b,i,k] X0[b,j,k] + b1[o]
// Only s2[b] = sum_o clw[128+o] * sum_k X2[b,o,k] is needed downstream.
__global__ __launch_bounds__(128) void k_cin1(const float* __restrict__ emb,
                                              const float* __restrict__ X1g,
                                              const float* __restrict__ W1t,
                                              const float* __restrict__ b1,
                                              const float* __restrict__ clw,
                                              float* __restrict__ s2) {
    __shared__ alignas(16) float X0s[NS * EMB];   // 208
    __shared__ alignas(16) float X1s[128 * 8];    // 1024
    __shared__ alignas(16) float Zc[32 * 26 * 8]; // 6656 = 26.6 KB (i-chunk of 32)
    __shared__ float red[2];
    int b = blockIdx.x, tid = threadIdx.x;
    for (int t = tid; t < NS * EMB; t += 128) X0s[t] = emb[b * (NS * EMB) + t];
    for (int t = tid; t < 1024; t += 128) X1s[t] = X1g[(long)b * 1024 + t];
    int o = tid;
    float a0 = 0, a1 = 0, a2 = 0, a3 = 0, a4 = 0, a5 = 0, a6 = 0, a7 = 0;
    const float4* Zv = (const float4*)Zc;
    for (int ic = 0; ic < 4; ic++) {
        __syncthreads();  // covers initial loads (ic=0) and prior chunk consumption
        for (int t = tid; t < 6656; t += 128) {
            int k = t & 7, p = t >> 3;
            int il = p / 26, j = p - il * 26;
            Zc[t] = X1s[(ic * 32 + il) * 8 + k] * X0s[j * 8 + k];
        }
        __syncthreads();
        const float* wp = W1t + ic * 832 * 128 + o;
#pragma unroll 4
        for (int pl = 0; pl < 832; pl++) {
            float w = wp[pl * 128];
            float4 za = Zv[2 * pl], zb = Zv[2 * pl + 1];
            a0 += w * za.x; a1 += w * za.y; a2 += w * za.z; a3 += w * za.w;
            a4 += w * zb.x; a5 += w * zb.y; a6 += w * zb.z; a7 += w * zb.w;
        }
    }
    float bias = b1[o];
    float s = (a0 + a1 + a2 + a3) + (a4 + a5 + a6 + a7) + 8.f * bias;
    float c = s * clw[128 + o];
    for (int off = 32; off; off >>= 1) c += __shfl_down(c, off, 64);
    if ((tid & 63) == 0) red[tid >> 6] = c;
    __syncthreads();
    if (tid == 0) s2[b] = red[0] + red[1];
}

// Fused DNN (221->256->128->64->1) + final combine + sigmoid. One block per batch row.
__global__ __launch_bounds__(256) void k_dnn(const float* __restrict__ inputs,
                                             const float* __restrict__ emb,
                                             const float* __restrict__ dW1, const float* __restrict__ db1,
                                             const float* __restrict__ dW2, const float* __restrict__ db2,
                                             const float* __restrict__ dW3, const float* __restrict__ db3,
                                             const float* __restrict__ dW4, const float* __restrict__ db4,
                                             const float* __restrict__ lin,
                                             const float* __restrict__ s1,
                                             const float* __restrict__ s2,
                                             const float* __restrict__ clb,
                                             float* __restrict__ out) {
    __shared__ float ins[221];
    __shared__ float h1[256];
    __shared__ float h2[128];
    __shared__ float h3[64];
    int b = blockIdx.x, tid = threadIdx.x;
    if (tid < ND) ins[tid] = inputs[b * NF + tid];
    for (int t = tid; t < NS * EMB; t += 256) ins[ND + t] = emb[b * (NS * EMB) + t];
    __syncthreads();
    // layer 1: 221 -> 256
    {
        float acc = db1[tid];
        for (int c = 0; c < 221; c++) acc += ins[c] * dW1[c * 256 + tid];
        h1[tid] = fmaxf(acc, 0.f);
    }
    __syncthreads();
    // layer 2: 256 -> 128
    if (tid < 128) {
        float acc = db2[tid];
        for (int c = 0; c < 256; c++) acc += h1[c] * dW2[c * 128 + tid];
        h2[tid] = fmaxf(acc, 0.f);
    }
    __syncthreads();
    // layer 3: 128 -> 64
    if (tid < 64) {
        float acc = db3[tid];
        for (int c = 0; c < 128; c++) acc += h2[c] * dW3[c * 64 + tid];
        h3[tid] = fmaxf(acc, 0.f);
    }
    __syncthreads();
    // layer 4: 64 -> 1, then combine
    if (tid < 64) {
        float a = h3[tid] * dW4[tid];
        for (int off = 32; off; off >>= 1) a += __shfl_down(a, off, 64);
        if (tid == 0) {
            float dense_out = fmaxf(a + db4[0], 0.f);
            float cin_out = fmaxf(s1[b] + s2[b] + clb[0], 0.f);
            float x = lin[b] + cin_out + dense_out;
            out[b] = 1.f / (1.f + expf(-x));
        }
    }
}

extern "C" void kernel_launch(void* const* d_in, const int* in_sizes, int n_in,
                              void* d_out, int out_size, void* d_ws, size_t ws_size,
                              hipStream_t stream) {
    const float* inputs = (const float*)d_in[0];
    const float* tables = (const float*)d_in[1];
    const float* lW     = (const float*)d_in[2];
    const float* lb     = (const float*)d_in[3];
    const float* W0     = (const float*)d_in[4];
    const float* b0     = (const float*)d_in[5];
    const float* W1c    = (const float*)d_in[6];
    const float* b1c    = (const float*)d_in[7];
    const float* clw    = (const float*)d_in[8];
    const float* clb    = (const float*)d_in[9];
    const float* dW1    = (const float*)d_in[10];
    const float* db1    = (const float*)d_in[11];
    const float* dW2    = (const float*)d_in[12];
    const float* db2    = (const float*)d_in[13];
    const float* dW3    = (const float*)d_in[14];
    const float* db3    = (const float*)d_in[15];
    const float* dW4    = (const float*)d_in[16];
    const float* db4    = (const float*)d_in[17];

    float* ws  = (float*)d_ws;
    float* emb = ws + OFF_EMB;
    float* X1  = ws + OFF_X1;
    float* lin = ws + OFF_LIN;
    float* s1  = ws + OFF_S1;
    float* s2  = ws + OFF_S2;
    float* W0t = ws + OFF_W0T;
    float* W1t = ws + OFF_W1T;

    k_transpose<<<2002, 256, 0, stream>>>(W0, W1c, W0t, W1t);
    k_gather<<<3328, 256, 0, stream>>>(inputs, tables, lW, lb, emb, lin);
    k_cin0<<<B, 128, 0, stream>>>(emb, W0t, b0, clw, X1, s1);
    k_cin1<<<B, 128, 0, stream>>>(emb, X1, W1t, b1c, clw, s2);
    k_dnn<<<B, 256, 0, stream>>>(inputs, emb, dW1, db1, dW2, db2, dW3, db3, dW4, db4,
                                 lin, s1, s2, clb, (float*)d_out);
}

// Round 2
// 265.693 us; speedup vs baseline: 3.7818x; 3.7818x over previous
//
#include <hip/hip_runtime.h>
#include <math.h>

#define B     4096
#define ND    13
#define NS    26
#define NF    39
#define EMB   8
#define VOCAB 100000

// ---------------- workspace layout (floats) ----------------
#define OFF_EMB   0          // B*NS*EMB = 851968
#define OFF_LIN   851968     // B = 4096
#define OFF_SCIN  856064     // B = 4096
#define OFF_V     860160     // 128*26 = 3328   v[i*26+j] = sum_o clw[128+o] W1[o,i,j]
#define OFF_A1    863488     // 676             A1[l*26+m] = sum_o clw[o] W0[o,l,m]
#define OFF_G     864164     // 26*676 = 17576  G[j*676 + l*26+m] = sum_i v[i,j] W0[i,l,m]
#define OFF_C2J   881740     // 26              c2j[j] = sum_i v[i,j] b0[i]
#define OFF_CST   881766     // 1               8*(c1b + c2b)
// total ~882K floats = 3.5 MB (well under ws)

// ---- precompute stage 1: v, A1, scalar consts ----
__global__ __launch_bounds__(256) void k_pre1(const float* __restrict__ W0,
                                              const float* __restrict__ W1,
                                              const float* __restrict__ b0,
                                              const float* __restrict__ b1,
                                              const float* __restrict__ clw,
                                              float* __restrict__ v,
                                              float* __restrict__ A1,
                                              float* __restrict__ cst) {
    int t = blockIdx.x * 256 + threadIdx.x;
    if (t < 3328) {
        float acc = 0.f;
        for (int o = 0; o < 128; o++) acc += clw[128 + o] * W1[o * 3328 + t];
        v[t] = acc;
    } else if (t < 3328 + 676) {
        int p = t - 3328;
        float acc = 0.f;
        for (int o = 0; o < 128; o++) acc += clw[o] * W0[o * 676 + p];
        A1[p] = acc;
    } else if (t == 3328 + 676) {
        float c1b = 0.f, c2b = 0.f;
        for (int o = 0; o < 128; o++) { c1b += clw[o] * b0[o]; c2b += clw[128 + o] * b1[o]; }
        cst[0] = 8.f * (c1b + c2b);
    }
}

// ---- precompute stage 2: G, c2j ----
__global__ __launch_bounds__(256) void k_pre2(const float* __restrict__ W0,
                                              const float* __restrict__ b0,
                                              const float* __restrict__ v,
                                              float* __restrict__ G,
                                              float* __restrict__ c2j) {
    int t = blockIdx.x * 256 + threadIdx.x;
    if (t < 17576) {
        int j = t / 676, p = t - j * 676;
        float acc = 0.f;
        for (int i = 0; i < 128; i++) acc += v[i * 26 + j] * W0[i * 676 + p];
        G[t] = acc;
    } else if (t < 17576 + 26) {
        int j = t - 17576;
        float acc = 0.f;
        for (int i = 0; i < 128; i++) acc += v[i * 26 + j] * b0[i];
        c2j[j] = acc;
    }
}

// ---- embedding gather + linear term ----
__global__ void k_gather(const float* __restrict__ inputs, const float* __restrict__ tables,
                         const float* __restrict__ lW, const float* __restrict__ lb,
                         float* __restrict__ emb, float* __restrict__ lin) {
    int t = blockIdx.x * 256 + threadIdx.x;
    if (t < B * NS * EMB) {
        int e = t & 7;
        int rest = t >> 3;
        int f = rest % NS;
        int b = rest / NS;
        int idx = (int)inputs[b * NF + ND + f];
        emb[t] = tables[((long)f * VOCAB + idx) * EMB + e];
    }
    if (t < B) {
        float acc = lb[0];
        for (int c = 0; c < NF; c++) acc += inputs[t * NF + c] * lW[c];
        lin[t] = acc;
    }
}

// ---- collapsed CIN: quadratic + cubic form per batch row ----
// scin[b] = sum_k x_k^T A1 x_k + sum_k sum_j x_j[k] (x_k^T G_j x_k)
//         + sum_j c2j[j] u[j] + cst
__global__ __launch_bounds__(256) void k_cin(const float* __restrict__ emb,
                                             const float* __restrict__ G,
                                             const float* __restrict__ A1,
                                             const float* __restrict__ c2j,
                                             const float* __restrict__ cst,
                                             float* __restrict__ scin) {
    __shared__ float xs[NS * EMB];   // x[l][k]
    __shared__ float red[4];
    int b = blockIdx.x, tid = threadIdx.x;
    if (tid < NS * EMB) xs[tid] = emb[b * (NS * EMB) + tid];
    __syncthreads();
    float partial = 0.f;
    for (int p = tid; p < 676; p += 256) {
        int l = p / 26, m = p - l * 26;
        float acc[8];
#pragma unroll
        for (int k = 0; k < 8; k++) acc[k] = 0.f;
#pragma unroll
        for (int j = 0; j < 26; j++) {
            float g = G[j * 676 + p];
#pragma unroll
            for (int k = 0; k < 8; k++) acc[k] += g * xs[j * 8 + k];
        }
        float a1 = A1[p];
#pragma unroll
        for (int k = 0; k < 8; k++)
            partial += (a1 + acc[k]) * xs[l * 8 + k] * xs[m * 8 + k];
    }
    if (tid < NS) {
        float u = 0.f;
#pragma unroll
        for (int k = 0; k < 8; k++) u += xs[tid * 8 + k];
        partial += c2j[tid] * u;
    }
    if (tid == 0) partial += cst[0];
    for (int off = 32; off; off >>= 1) partial += __shfl_down(partial, off, 64);
    if ((tid & 63) == 0) red[tid >> 6] = partial;
    __syncthreads();
    if (tid == 0) scin[b] = red[0] + red[1] + red[2] + red[3];
}

// ---- fused DNN, 4 rows per block ----
#define RPB 4
__global__ __launch_bounds__(256) void k_dnn(const float* __restrict__ inputs,
                                             const float* __restrict__ emb,
                                             const float* __restrict__ dW1, const float* __restrict__ db1,
                                             const float* __restrict__ dW2, const float* __restrict__ db2,
                                             const float* __restrict__ dW3, const float* __restrict__ db3,
                                             const float* __restrict__ dW4, const float* __restrict__ db4,
                                             const float* __restrict__ lin,
                                             const float* __restrict__ scin,
                                             const float* __restrict__ clb,
                                             float* __restrict__ out) {
    __shared__ float ins[RPB][224];
    __shared__ float h1[RPB][256];
    __shared__ float h2[RPB][128];
    __shared__ float h3[RPB][64];
    int b0r = blockIdx.x * RPB, tid = threadIdx.x;
    for (int t = tid; t < RPB * ND; t += 256) {
        int r = t / ND, c = t - r * ND;
        ins[r][c] = inputs[(b0r + r) * NF + c];
    }
    for (int t = tid; t < RPB * NS * EMB; t += 256) {
        int r = t >> 8;            // 208 < 256, but use exact: t / 208
        r = t / 208; int c = t - r * 208;
        ins[r][ND + c] = emb[(b0r + r) * 208 + c];
    }
    __syncthreads();
    // layer 1: 221 -> 256, thread = out unit, 4 rows each
    {
        float bias = db1[tid];
        float a0 = bias, a1 = bias, a2 = bias, a3 = bias;
        for (int c = 0; c < 221; c++) {
            float w = dW1[c * 256 + tid];
            a0 += ins[0][c] * w; a1 += ins[1][c] * w;
            a2 += ins[2][c] * w; a3 += ins[3][c] * w;
        }
        h1[0][tid] = fmaxf(a0, 0.f); h1[1][tid] = fmaxf(a1, 0.f);
        h1[2][tid] = fmaxf(a2, 0.f); h1[3][tid] = fmaxf(a3, 0.f);
    }
    __syncthreads();
    // layer 2: 256 -> 128, thread = (out unit, row pair)
    {
        int o = tid & 127, rr = (tid >> 7) * 2;
        float bias = db2[o];
        float a0 = bias, a1 = bias;
        for (int c = 0; c < 256; c++) {
            float w = dW2[c * 128 + o];
            a0 += h1[rr][c] * w; a1 += h1[rr + 1][c] * w;
        }
        h2[rr][o] = fmaxf(a0, 0.f); h2[rr + 1][o] = fmaxf(a1, 0.f);
    }
    __syncthreads();
    // layer 3: 128 -> 64, thread = (out unit, row)
    {
        int o = tid & 63, r = tid >> 6;
        float a = db3[o];
        for (int c = 0; c < 128; c++) a += h2[r][c] * dW3[c * 64 + o];
        h3[r][o] = fmaxf(a, 0.f);
    }
    __syncthreads();
    // layer 4 + combine: one wave per row
    {
        int r = tid >> 6, lane = tid & 63;
        float a = h3[r][lane] * dW4[lane];
        for (int off = 32; off; off >>= 1) a += __shfl_down(a, off, 64);
        if (lane == 0) {
            int b = b0r + r;
            float dense_out = fmaxf(a + db4[0], 0.f);
            float cin_out = fmaxf(scin[b] + clb[0], 0.f);
            float x = lin[b] + cin_out + dense_out;
            out[b] = 1.f / (1.f + expf(-x));
        }
    }
}

extern "C" void kernel_launch(void* const* d_in, const int* in_sizes, int n_in,
                              void* d_out, int out_size, void* d_ws, size_t ws_size,
                              hipStream_t stream) {
    const float* inputs = (const float*)d_in[0];
    const float* tables = (const float*)d_in[1];
    const float* lW     = (const float*)d_in[2];
    const float* lb     = (const float*)d_in[3];
    const float* W0     = (const float*)d_in[4];
    const float* b0     = (const float*)d_in[5];
    const float* W1c    = (const float*)d_in[6];
    const float* b1c    = (const float*)d_in[7];
    const float* clw    = (const float*)d_in[8];
    const float* clb    = (const float*)d_in[9];
    const float* dW1    = (const float*)d_in[10];
    const float* db1    = (const float*)d_in[11];
    const float* dW2    = (const float*)d_in[12];
    const float* db2    = (const float*)d_in[13];
    const float* dW3    = (const float*)d_in[14];
    const float* db3    = (const float*)d_in[15];
    const float* dW4    = (const float*)d_in[16];
    const float* db4    = (const float*)d_in[17];

    float* ws   = (float*)d_ws;
    float* emb  = ws + OFF_EMB;
    float* lin  = ws + OFF_LIN;
    float* scin = ws + OFF_SCIN;
    float* v    = ws + OFF_V;
    float* A1   = ws + OFF_A1;
    float* G    = ws + OFF_G;
    float* c2j  = ws + OFF_C2J;
    float* cst  = ws + OFF_CST;

    k_pre1<<<16, 256, 0, stream>>>(W0, W1c, b0, b1c, clw, v, A1, cst);
    k_pre2<<<70, 256, 0, stream>>>(W0, b0, v, G, c2j);
    k_gather<<<3328, 256, 0, stream>>>(inputs, tables, lW, lb, emb, lin);
    k_cin<<<B, 256, 0, stream>>>(emb, G, A1, c2j, cst, scin);
    k_dnn<<<B / RPB, 256, 0, stream>>>(inputs, emb, dW1, db1, dW2, db2, dW3, db3, dW4, db4,
                                       lin, scin, clb, (float*)d_out);
}